// Round 13
// baseline (178.153 us; speedup 1.0000x reference)
//
#include <hip/hip_runtime.h>

// CrossAttentionGAT — algebraically collapsed; edge path = coarse counting-bin
// (128 buckets of 64 nodes) + LDS-privatized per-bucket segment reduction.
// Round-13: coalesced bin scatter. r12's bin role emitted 1M single 4B random
// global writes (partial-line RMW at L2). Now: LDS-stage records grouped by
// bucket (prefix-sum over the histogram), then copy out contiguous per-bucket
// runs (~16 consecutive records -> 64B+ segments). Bin format in global is
// unchanged (kb packed in bits 19-25 during staging, masked on copy-out).
// All other kernels byte-identical to r12 (178.1us verified).
// 6 dispatches: k_pre + k_binA + k_den + k_waccG + k_memb + k_out.
//
// mean(cross1) = mean(emb2) @ Wl + bl   (softmax col-sums == 1)
// mean(cross2) = mean(emb1) @ Wl + bl   (softmax row-sums == 1)
// mean(emb)    = (1/N) * sum_k g[head,k] * W[k, head*C+c] + b
//   g[head,k]  = sum_n w[n,head] x[n,k],  w[n,head] = sum_{e: src=n} alpha_e[head]

#define NN 8192
#define EE 262144
#define NEG 0.2f

#define BKT 128           // node buckets per graph
#define RNG (NN / BKT)    // 64 nodes per bucket
#define CAP 2560          // bucket capacity: mean 2048 + 11 sigma
#define CHK (EE / 128)    // 2048 edges per bin chunk (= 4 per thread at 512)

// ---------------- ws layout (4-byte units) ----------------
#define U_CNT   0                        // 2 graphs x {D,S} x BKT ints (k_pre zeroes)
#define U_GACC  (U_CNT + 4*BKT)          // 2*1024 floats (k_pre zeroes)
#define U_U     (U_GACC + 2048)          // 2*2048 floats: u[g][sd*1024+head*128+k]
#define U_MEMB  (U_U + 2*2048)           // 2*1024 floats (fully written by k_memb)
#define U_ASRC  (U_MEMB + 2048)          // 2*NN*8 floats
#define U_ADST  (U_ASRC + 2*NN*8)        // 2*NN*8 floats
#define U_PR    (U_ADST + 2*NN*8)        // 2*NN*16 floats: (adst,rden) float2
#define U_BIND  (U_PR + 2*NN*16)         // 2*BKT*CAP ints
#define U_BINS  (U_BIND + 2*BKT*CAP)     // 2*BKT*CAP ints

// K0: blk 0 zeroes cnt+gacc; blks 1..4 compute u for (g,sd).
__global__ __launch_bounds__(512) void k_pre(
    const float* __restrict__ W1, const float* __restrict__ as1,
    const float* __restrict__ ad1,
    const float* __restrict__ W2, const float* __restrict__ as2,
    const float* __restrict__ ad2,
    int* __restrict__ cnt, float* __restrict__ gacc, float* __restrict__ u) {
  int t = threadIdx.x;
  if (blockIdx.x == 0) {
    cnt[t] = 0;                         // 4*BKT = 512 ints
#pragma unroll
    for (int i = t; i < 2048; i += 512) gacc[i] = 0.f;
    return;
  }
  int id = blockIdx.x - 1;              // 0..3
  int g = id >> 1, sd = id & 1;
  const float* Wg = g ? W2 : W1;
  const float* att = g ? (sd ? ad2 : as2) : (sd ? ad1 : as1);
  float* uo = u + g * 2048 + sd * 1024;
  for (int o = t; o < 1024; o += 512) {
    int head = o >> 7, k = o & 127;
    const float4* wr = (const float4*)(Wg + (size_t)k * 1024 + head * 128);
    const float4* ar = (const float4*)(att + head * 128);
    float s = 0.f;
#pragma unroll 8
    for (int c = 0; c < 32; ++c) {
      float4 w4 = wr[c], a4 = ar[c];
      s += w4.x * a4.x + w4.y * a4.y + w4.z * a4.z + w4.w * a4.w;
    }
    uo[o] = s;
  }
}

union SMemBA {
  struct {
    int hD[BKT]; int hS[BKT]; int bD[BKT]; int bS[BKT];
    int oD[BKT]; int oS[BKT];            // inclusive prefix sums
    int stD[CHK]; int stS[CHK];          // bucket-grouped staged records
  } bin;                                 // 19 KB
  struct { float xs[64][129]; float us[16][128]; } a;   // 41.2 KB
};

// K1: fused bin ∥ a. Grid (256, 2), 512 thr, co-resident.
// x<128: single-pass bin of edge chunk x with LDS-staged coalesced scatter.
// x>=128: a_src/a_dst for node tile (x-128), u staged from global.
__global__ __launch_bounds__(512) void k_binA(
    const int* __restrict__ ei1, const int* __restrict__ ei2,
    const float* __restrict__ x1, const float* __restrict__ x2,
    const float* __restrict__ u,
    int* __restrict__ cnt, int* __restrict__ binD, int* __restrict__ binS,
    float* __restrict__ asrc, float* __restrict__ adst) {
  __shared__ SMemBA sm;
  int g = blockIdx.y;
  int t = threadIdx.x;

  if (blockIdx.x >= 128) {
    // ------------- a role: 64-node tile, u from global -------------
    int cb = blockIdx.x - 128;
    const float* ug = u + g * 2048;
    for (int i = t; i < 2048; i += 512) sm.a.us[i >> 7][i & 127] = ug[i];
    const float* x = g ? x2 : x1;
    const int n0 = cb * 64;
    const float4* xb4 = (const float4*)(x + (size_t)n0 * 128);
    for (int i = t; i < 64 * 32; i += 512) {
      float4 v = xb4[i];
      int r = i >> 5, c = (i & 31) * 4;
      sm.a.xs[r][c] = v.x; sm.a.xs[r][c + 1] = v.y;
      sm.a.xs[r][c + 2] = v.z; sm.a.xs[r][c + 3] = v.w;
    }
    __syncthreads();
    int nl = t & 63;
    int j0 = (t >> 6) * 2;            // 8 groups x 2 outputs = 16 (8 src + 8 dst)
    float a0 = 0.f, a1 = 0.f;
#pragma unroll 4
    for (int k = 0; k < 128; ++k) {
      float xv = sm.a.xs[nl][k];
      a0 += xv * sm.a.us[j0 + 0][k];
      a1 += xv * sm.a.us[j0 + 1][k];
    }
    int n = n0 + nl;
    float* outp = (j0 < 8) ? (asrc + g * (NN * 8) + n * 8 + j0)
                           : (adst + g * (NN * 8) + n * 8 + (j0 - 8));
    outp[0] = a0; outp[1] = a1;
    return;
  }

  // ------------- bin role: histogram -> scan -> LDS stage -> coalesced out ---
  const int* ei = g ? ei2 : ei1;
  for (int i = t; i < BKT; i += 512) { sm.bin.hD[i] = 0; sm.bin.hS[i] = 0; }
  __syncthreads();
  int e0 = blockIdx.x * CHK;
  int sE[4], dE[4], lD[4], lS[4];
#pragma unroll
  for (int uu = 0; uu < 4; ++uu) {
    int i = e0 + uu * 512 + t;
    sE[uu] = ei[i];
    dE[uu] = ei[EE + i];
  }
#pragma unroll
  for (int uu = 0; uu < 4; ++uu) {
    lD[uu] = atomicAdd(&sm.bin.hD[dE[uu] >> 6], 1);
    lS[uu] = atomicAdd(&sm.bin.hS[sE[uu] >> 6], 1);
  }
  __syncthreads();
  // global reservation + init inclusive scan arrays
  if (t < BKT) {
    sm.bin.bD[t] = atomicAdd(cnt + (2 * g + 0) * BKT + t, sm.bin.hD[t]);
    sm.bin.bS[t] = atomicAdd(cnt + (2 * g + 1) * BKT + t, sm.bin.hS[t]);
    sm.bin.oD[t] = sm.bin.hD[t];
    sm.bin.oS[t] = sm.bin.hS[t];
  }
  __syncthreads();
  // inclusive prefix sum over 128 buckets (log-step, uniform loop)
  for (int off = 1; off < BKT; off <<= 1) {
    int vD = 0, vS = 0;
    bool act = (t < BKT) && (t >= off);
    if (act) { vD = sm.bin.oD[t - off]; vS = sm.bin.oS[t - off]; }
    __syncthreads();
    if (act) { sm.bin.oD[t] += vD; sm.bin.oS[t] += vS; }
    __syncthreads();
  }
  // LDS scatter: slot = exclusive_base(kb) + local_rank; kb packed in bits 19+
#pragma unroll
  for (int uu = 0; uu < 4; ++uu) {
    int kb = dE[uu] >> 6;
    sm.bin.stD[sm.bin.oD[kb] - sm.bin.hD[kb] + lD[uu]] =
        (kb << 19) | (sE[uu] << 6) | (dE[uu] & 63);
    kb = sE[uu] >> 6;
    sm.bin.stS[sm.bin.oS[kb] - sm.bin.hS[kb] + lS[uu]] =
        (kb << 19) | (dE[uu] << 6) | (sE[uu] & 63);
  }
  __syncthreads();
  // coalesced copy-out: consecutive slots of a bucket run -> consecutive global
  int* bdg = binD + (size_t)g * BKT * CAP;
  int* bsg = binS + (size_t)g * BKT * CAP;
  for (int i = t; i < CHK; i += 512) {
    int r = sm.bin.stD[i];
    int kb = r >> 19;
    int pos = i - (sm.bin.oD[kb] - sm.bin.hD[kb]);
    bdg[kb * CAP + sm.bin.bD[kb] + pos] = r & 0x7FFFF;
    r = sm.bin.stS[i];
    kb = r >> 19;
    pos = i - (sm.bin.oS[kb] - sm.bin.hS[kb]);
    bsg[kb * CAP + sm.bin.bS[kb] + pos] = r & 0x7FFFF;
  }
}

// K2: per dst-bucket denominator -> pr = (adst, 1/den). 1024 thr.
__global__ __launch_bounds__(1024) void k_den(
    const int* __restrict__ cnt, const int* __restrict__ binD,
    const float* __restrict__ asrc, const float* __restrict__ adst,
    float* __restrict__ pr) {
  int gph = blockIdx.y, b = blockIdx.x;
  int lo = b * RNG;
  const float* as = asrc + gph * (NN * 8);
  const float* ad = adst + gph * (NN * 8);
  float2* prg = (float2*)pr + (size_t)gph * (NN * 8);
  __shared__ float den[RNG * 8];
  __shared__ float ads[RNG * 8];
  int t = threadIdx.x;
  if (t < RNG * 8) {
    float avv = ad[lo * 8 + t];
    float v = as[lo * 8 + t] + avv;      // self loop (s == d)
    v = v > 0.f ? v : NEG * v;
    ads[t] = avv;
    den[t] = __expf(v);
  }
  __syncthreads();
  int n = cnt[(2 * gph + 0) * BKT + b];
  const int* recs = binD + (size_t)gph * BKT * CAP + b * CAP;
  int rid = t >> 3, h = t & 7;           // rid 0..127
  for (int base = 0; base < n; base += 512) {
    int rv[4]; bool ok[4]; float sv[4];
#pragma unroll
    for (int uu = 0; uu < 4; ++uu) {
      int i = base + uu * 128 + rid;
      ok[uu] = i < n;
      rv[uu] = ok[uu] ? recs[i] : 0;
    }
#pragma unroll
    for (int uu = 0; uu < 4; ++uu)
      sv[uu] = ok[uu] ? as[(rv[uu] >> 6) * 8 + h] : 0.f;
#pragma unroll
    for (int uu = 0; uu < 4; ++uu) {
      if (ok[uu]) {
        int dl = rv[uu] & 63;
        float v = sv[uu] + ads[dl * 8 + h];
        v = v > 0.f ? v : NEG * v;
        atomicAdd(&den[dl * 8 + h], __expf(v));
      }
    }
  }
  __syncthreads();
  if (t < RNG * 8)
    prg[lo * 8 + t] = make_float2(ads[t], 1.0f / den[t]);
}

// K3: per src-bucket alpha-sum (LDS wv) + fused g-reduce. 1024 thr.
__global__ __launch_bounds__(1024) void k_waccG(
    const int* __restrict__ cnt, const int* __restrict__ binS,
    const float* __restrict__ asrc, const float* __restrict__ pr,
    const float* __restrict__ x1, const float* __restrict__ x2,
    float* __restrict__ gacc) {
  int gph = blockIdx.y, b = blockIdx.x;
  int lo = b * RNG;
  const float* as = asrc + gph * (NN * 8);
  const float2* prg = (const float2*)pr + (size_t)gph * (NN * 8);
  __shared__ float wv[RNG * 8];
  __shared__ float asx[RNG * 8];
  int t = threadIdx.x;
  if (t < RNG * 8) {
    float sva = as[lo * 8 + t];
    float2 f2 = prg[lo * 8 + t];         // (adst[n,h], rden[n,h])
    float v = sva + f2.x;                // self loop
    v = v > 0.f ? v : NEG * v;
    asx[t] = sva;
    wv[t] = __expf(v) * f2.y;
  }
  __syncthreads();
  int n = cnt[(2 * gph + 1) * BKT + b];
  const int* recs = binS + (size_t)gph * BKT * CAP + b * CAP;
  int rid = t >> 3, h = t & 7;           // rid 0..127
  for (int base = 0; base < n; base += 512) {
    int rv[4]; bool ok[4]; float2 pv[4];
#pragma unroll
    for (int uu = 0; uu < 4; ++uu) {
      int i = base + uu * 128 + rid;
      ok[uu] = i < n;
      rv[uu] = ok[uu] ? recs[i] : 0;
    }
#pragma unroll
    for (int uu = 0; uu < 4; ++uu)
      pv[uu] = ok[uu] ? prg[(size_t)(rv[uu] >> 6) * 8 + h] : make_float2(0.f, 0.f);
#pragma unroll
    for (int uu = 0; uu < 4; ++uu) {
      if (ok[uu]) {
        int sl = rv[uu] & 63;
        float v = asx[sl * 8 + h] + pv[uu].x;
        v = v > 0.f ? v : NEG * v;
        atomicAdd(&wv[sl * 8 + h], __expf(v) * pv[uu].y);
      }
    }
  }
  __syncthreads();
  // fused g-reduce: this bucket's 64 nodes; thread = (h0, k), 1 head each
  const float* x = gph ? x2 : x1;
  float* gg = gacc + gph * 1024;
  int k = t & 127;
  int h0 = t >> 7;                     // 0..7
  int n0 = b * RNG;
  float a0 = 0.f;
#pragma unroll 4
  for (int nl = 0; nl < RNG; ++nl)
    a0 += x[(size_t)(n0 + nl) * 128 + k] * wv[nl * 8 + h0];
  atomicAdd(gg + h0 * 128 + k, a0);
}

// K4: memb[g][e] = (1/N) sum_{k<128} gacc[g,head(e),k] W[k,e] + b[e].
__global__ __launch_bounds__(512) void k_memb(
    const float* __restrict__ gacc,
    const float* __restrict__ W1, const float* __restrict__ b1,
    const float* __restrict__ W2, const float* __restrict__ b2,
    float* __restrict__ memb) {
  int g = blockIdx.y;
  int e0 = blockIdx.x * 64;
  const float* W = g ? W2 : W1;
  const float* bb = g ? b2 : b1;
  const float* gr = gacc + g * 1024 + (e0 >> 7) * 128;   // head const per block
  __shared__ float pm[8][64];
  int t = threadIdx.x;
  int el = t & 63, kc = t >> 6;        // kc = 0..7
  int e = e0 + el;
  float s = 0.f;
#pragma unroll
  for (int k = kc * 16; k < kc * 16 + 16; ++k)
    s += gr[k] * W[(size_t)k * 1024 + e];
  pm[kc][el] = s;
  __syncthreads();
  if (t < 64) {
    float acc = pm[0][el];
#pragma unroll
    for (int q = 1; q < 8; ++q) acc += pm[q][el];
    memb[g * 1024 + e] = acc * (1.0f / (float)NN) + bb[e];
  }
}

// K5: out = [memb(g2); memb(g1)] @ Wl + bl. 8 blocks x 32 outputs, non-atomic.
__global__ __launch_bounds__(512) void k_out(
    const float* __restrict__ memb, const float* __restrict__ Wl,
    const float* __restrict__ bl, float* __restrict__ out) {
  __shared__ float ml[1024];
  __shared__ float po[16][32];
  int b = blockIdx.x;                  // 0..7
  int t = threadIdx.x;
  const float* m = (b < 4) ? (memb + 1024) : memb;   // out[0..127] <- graph2
  for (int i = t; i < 1024; i += 512) ml[i] = m[i];
  __syncthreads();
  int ol = t & 31, kc = t >> 5;        // kc = 0..15, 64 k each
  int o = b * 32 + ol;
  int j = o & 127;
  float s = 0.f;
#pragma unroll 8
  for (int k = kc * 64; k < kc * 64 + 64; ++k)
    s += ml[k] * Wl[(size_t)k * 128 + j];
  po[kc][ol] = s;
  __syncthreads();
  if (t < 32) {
    float acc = po[0][t];
#pragma unroll
    for (int q = 1; q < 16; ++q) acc += po[q][t];
    out[b * 32 + t] = acc + bl[(b * 32 + t) & 127];
  }
}

extern "C" void kernel_launch(void* const* d_in, const int* in_sizes, int n_in,
                              void* d_out, int out_size, void* d_ws, size_t ws_size,
                              hipStream_t stream) {
  const float* x1  = (const float*)d_in[0];
  const int*   ei1 = (const int*)d_in[1];
  const float* W1  = (const float*)d_in[2];
  const float* as1 = (const float*)d_in[3];
  const float* ad1 = (const float*)d_in[4];
  const float* b1  = (const float*)d_in[5];
  const float* x2  = (const float*)d_in[6];
  const int*   ei2 = (const int*)d_in[7];
  const float* W2  = (const float*)d_in[8];
  const float* as2 = (const float*)d_in[9];
  const float* ad2 = (const float*)d_in[10];
  const float* b2  = (const float*)d_in[11];
  const float* Wl  = (const float*)d_in[12];
  const float* bl  = (const float*)d_in[13];
  float* out = (float*)d_out;

  int*   cnt  = (int*)d_ws + U_CNT;
  float* gacc = (float*)d_ws + U_GACC;
  float* u    = (float*)d_ws + U_U;
  float* memb = (float*)d_ws + U_MEMB;
  float* asrc = (float*)d_ws + U_ASRC;
  float* adst = (float*)d_ws + U_ADST;
  float* pr   = (float*)d_ws + U_PR;
  int*   binD = (int*)d_ws + U_BIND;
  int*   binS = (int*)d_ws + U_BINS;

  k_pre<<<5, 512, 0, stream>>>(W1, as1, ad1, W2, as2, ad2, cnt, gacc, u);
  k_binA<<<dim3(256, 2), 512, 0, stream>>>(ei1, ei2, x1, x2, u,
                                           cnt, binD, binS, asrc, adst);
  k_den<<<dim3(BKT, 2), 1024, 0, stream>>>(cnt, binD, asrc, adst, pr);
  k_waccG<<<dim3(BKT, 2), 1024, 0, stream>>>(cnt, binS, asrc, pr, x1, x2, gacc);
  k_memb<<<dim3(16, 2), 512, 0, stream>>>(gacc, W1, b1, W2, b2, memb);
  k_out<<<8, 512, 0, stream>>>(memb, Wl, bl, out);
}